// Round 1
// baseline (322.133 us; speedup 1.0000x reference)
//
#include <hip/hip_runtime.h>

typedef unsigned short u16;
using short8 = __attribute__((ext_vector_type(8))) short;
using f32x4  = __attribute__((ext_vector_type(4))) float;

#define S_LEN 4096
#define EMB   768
#define NH    12
#define DH    64

__device__ __forceinline__ u16 f2bf(float f) {
  unsigned int u = __builtin_bit_cast(unsigned int, f);
  u += 0x7fffu + ((u >> 16) & 1u);
  return (u16)(u >> 16);
}

__device__ __forceinline__ f32x4 mfma16(short8 a, short8 b, f32x4 c) {
  return __builtin_amdgcn_mfma_f32_16x16x32_bf16(a, b, c, 0, 0, 0);
}

// ---------------- conversion / transpose kernels ----------------

__global__ void k_conv_x(const float* __restrict__ x, u16* __restrict__ xb, int n) {
  int i = blockIdx.x * 256 + threadIdx.x;
  if (i < n) xb[i] = f2bf(x[i]);
}

// wt[n][k] = w[k][n];  w is [rows=K][cols=N], wt is [cols][rows]
__global__ void k_transpose_w(const float* __restrict__ w, u16* __restrict__ wt,
                              int rows, int cols) {
  int i = blockIdx.x * 256 + threadIdx.x;
  if (i < rows * cols) {
    int n = i / rows, k = i - n * rows;
    wt[i] = f2bf(w[(size_t)k * cols + n]);
  }
}

// ---------------- QKV GEMM + bias + RoPE epilogue ----------------
// A: x bf16 [4096][768]; Bt: Wqkv^T bf16 [2304][768]; bias f32 [2304]
// Writes Q,K (RoPE'd) as [H][S][64] bf16, V transposed as [H][64][S] bf16.
__global__ __launch_bounds__(256) void k_qkv(const u16* __restrict__ A,
                                             const u16* __restrict__ Bt,
                                             const float* __restrict__ bias,
                                             u16* __restrict__ Qb,
                                             u16* __restrict__ Kb,
                                             u16* __restrict__ Vt) {
  __shared__ u16 As[128][40];
  __shared__ u16 Bs[128][40];
  int t = threadIdx.x;
  int w = t >> 6, lane = t & 63, g = lane >> 4, c = lane & 15;
  int wr = w >> 1, wc = w & 1;
  int bm = blockIdx.x * 128, bn = blockIdx.y * 128;

  f32x4 acc[4][4];
#pragma unroll
  for (int m = 0; m < 4; m++)
#pragma unroll
    for (int n = 0; n < 4; n++) acc[m][n] = (f32x4){0.f, 0.f, 0.f, 0.f};

  int srow = t >> 1, sseg = (t & 1) * 16;
  for (int bk = 0; bk < EMB; bk += 32) {
    const u16* ga = A  + (size_t)(bm + srow) * EMB + bk + sseg;
    const u16* gb = Bt + (size_t)(bn + srow) * EMB + bk + sseg;
    short8 a0 = *(const short8*)ga, a1 = *(const short8*)(ga + 8);
    short8 b0 = *(const short8*)gb, b1 = *(const short8*)(gb + 8);
    __syncthreads();
    *(short8*)&As[srow][sseg] = a0; *(short8*)&As[srow][sseg + 8] = a1;
    *(short8*)&Bs[srow][sseg] = b0; *(short8*)&Bs[srow][sseg + 8] = b1;
    __syncthreads();
    short8 af[4], bf[4];
#pragma unroll
    for (int m = 0; m < 4; m++) af[m] = *(const short8*)&As[wr * 64 + m * 16 + c][g * 8];
#pragma unroll
    for (int n = 0; n < 4; n++) bf[n] = *(const short8*)&Bs[wc * 64 + n * 16 + c][g * 8];
#pragma unroll
    for (int m = 0; m < 4; m++)
#pragma unroll
      for (int n = 0; n < 4; n++) acc[m][n] = mfma16(af[m], bf[n], acc[m][n]);
  }

  // epilogue: each wave's 64-col block lies in exactly one head of one section
  int colbase = bn + wc * 64;
  int sec = colbase / EMB;               // 0=Q 1=K 2=V
  int hh  = (colbase % EMB) / DH;
  float invf[2];
#pragma unroll
  for (int n = 0; n < 2; n++) {
    int d1 = n * 16 + c;                  // < 32
    invf[n] = exp2f(-(float)d1 * (13.287712379549449f / 32.0f)); // 10000^(-d1/32)
  }
#pragma unroll
  for (int m = 0; m < 4; m++) {
    int rowb = bm + wr * 64 + m * 16 + 4 * g;
#pragma unroll
    for (int e = 0; e < 4; e++) {
      int srw = rowb + e;
      float v[4];
#pragma unroll
      for (int n = 0; n < 4; n++) v[n] = acc[m][n][e] + bias[colbase + n * 16 + c];
      if (sec == 2) {
#pragma unroll
        for (int n = 0; n < 4; n++)
          Vt[(size_t)(hh * DH + n * 16 + c) * S_LEN + srw] = f2bf(v[n]);
      } else {
        u16* dst = (sec == 0) ? Qb : Kb;
        size_t base = ((size_t)hh * S_LEN + srw) * DH;
#pragma unroll
        for (int n = 0; n < 2; n++) {
          int d1 = n * 16 + c;
          float ang = (float)srw * invf[n];
          float sn, cs;
          sincosf(ang, &sn, &cs);
          float o1 = v[n] * cs - v[n + 2] * sn;
          float o2 = v[n + 2] * cs + v[n] * sn;
          dst[base + d1]      = f2bf(o1);
          dst[base + d1 + 32] = f2bf(o2);
        }
      }
    }
  }
}

// ---------------- flash attention ----------------
// Q,K: [H][S][64] bf16 (RoPE applied); Vt: [H][64][S] bf16; O: [S][768] bf16
__global__ __launch_bounds__(256) void k_attn(const u16* __restrict__ Q,
                                              const u16* __restrict__ K,
                                              const u16* __restrict__ Vt,
                                              u16* __restrict__ O) {
  int w = threadIdx.x >> 6;
  int lane = threadIdx.x & 63, g = lane >> 4, c = lane & 15;
  int h = blockIdx.x >> 6;
  int grp = blockIdx.x & 63;
  int qb = grp + 64 * w;                 // balance causal work across blocks

  __shared__ u16 P[4][16][40];

  const u16* Qh = Q  + (size_t)h * S_LEN * DH;
  const u16* Kh = K  + (size_t)h * S_LEN * DH;
  const u16* Vh = Vt + (size_t)h * DH * S_LEN;

  short8 qf[2];
  qf[0] = *(const short8*)(Qh + (size_t)(qb * 16 + c) * DH + g * 8);
  qf[1] = *(const short8*)(Qh + (size_t)(qb * 16 + c) * DH + 32 + g * 8);

  float m_r[4], l_r[4];
  f32x4 acc[4];
#pragma unroll
  for (int e = 0; e < 4; e++) { m_r[e] = -1e30f; l_r[e] = 0.f; }
#pragma unroll
  for (int n = 0; n < 4; n++) acc[n] = (f32x4){0.f, 0.f, 0.f, 0.f};

  int kvend = qb * 16 + 16;
  for (int kv0 = 0; kv0 < kvend; kv0 += 32) {
    f32x4 sc[2];
#pragma unroll
    for (int j2 = 0; j2 < 2; j2++) {
      const u16* kp = Kh + (size_t)(kv0 + j2 * 16 + c) * DH + g * 8;
      short8 k0 = *(const short8*)kp;
      short8 k1 = *(const short8*)(kp + 32);
      f32x4 z = (f32x4){0.f, 0.f, 0.f, 0.f};
      z = mfma16(qf[0], k0, z);
      z = mfma16(qf[1], k1, z);
      sc[j2] = z;
    }
    float fac[4];
#pragma unroll
    for (int e = 0; e < 4; e++) {
      int qrow = qb * 16 + 4 * g + e;
      float s0 = sc[0][e] * 0.125f;
      float s1 = sc[1][e] * 0.125f;
      if (kv0 + c > qrow)      s0 = -1e30f;
      if (kv0 + 16 + c > qrow) s1 = -1e30f;
      float mx = fmaxf(s0, s1);
      mx = fmaxf(mx, __shfl_xor(mx, 1));
      mx = fmaxf(mx, __shfl_xor(mx, 2));
      mx = fmaxf(mx, __shfl_xor(mx, 4));
      mx = fmaxf(mx, __shfl_xor(mx, 8));
      float nm = fmaxf(m_r[e], mx);
      float f = __expf(m_r[e] - nm);
      float p0 = __expf(s0 - nm);
      float p1 = __expf(s1 - nm);
      float sum = p0 + p1;
      sum += __shfl_xor(sum, 1);
      sum += __shfl_xor(sum, 2);
      sum += __shfl_xor(sum, 4);
      sum += __shfl_xor(sum, 8);
      l_r[e] = l_r[e] * f + sum;
      m_r[e] = nm;
      fac[e] = f;
      P[w][4 * g + e][c]      = f2bf(p0);
      P[w][4 * g + e][16 + c] = f2bf(p1);
    }
#pragma unroll
    for (int n = 0; n < 4; n++)
#pragma unroll
      for (int e = 0; e < 4; e++) acc[n][e] *= fac[e];
    asm volatile("s_waitcnt lgkmcnt(0)" ::: "memory");
    __builtin_amdgcn_sched_barrier(0);
    short8 pa = *(const short8*)&P[w][c][g * 8];
#pragma unroll
    for (int n = 0; n < 4; n++) {
      const u16* vp = Vh + (size_t)(n * 16 + c) * S_LEN + kv0 + g * 8;
      short8 vf = *(const short8*)vp;
      acc[n] = mfma16(pa, vf, acc[n]);
    }
  }
#pragma unroll
  for (int n = 0; n < 4; n++)
#pragma unroll
    for (int e = 0; e < 4; e++) {
      int srw = qb * 16 + 4 * g + e;
      float val = acc[n][e] / l_r[e];
      O[(size_t)srw * EMB + h * DH + n * 16 + c] = f2bf(val);
    }
}

// ---------------- output projection ----------------
// A: O bf16 [4096][768]; Bt: Wout^T bf16 [768][768]; bias f32 [768]; out f32
__global__ __launch_bounds__(256) void k_out(const u16* __restrict__ A,
                                             const u16* __restrict__ Bt,
                                             const float* __restrict__ bias,
                                             float* __restrict__ out) {
  __shared__ u16 As[128][40];
  __shared__ u16 Bs[128][40];
  int t = threadIdx.x;
  int w = t >> 6, lane = t & 63, g = lane >> 4, c = lane & 15;
  int wr = w >> 1, wc = w & 1;
  int bm = blockIdx.x * 128, bn = blockIdx.y * 128;

  f32x4 acc[4][4];
#pragma unroll
  for (int m = 0; m < 4; m++)
#pragma unroll
    for (int n = 0; n < 4; n++) acc[m][n] = (f32x4){0.f, 0.f, 0.f, 0.f};

  int srow = t >> 1, sseg = (t & 1) * 16;
  for (int bk = 0; bk < EMB; bk += 32) {
    const u16* ga = A  + (size_t)(bm + srow) * EMB + bk + sseg;
    const u16* gb = Bt + (size_t)(bn + srow) * EMB + bk + sseg;
    short8 a0 = *(const short8*)ga, a1 = *(const short8*)(ga + 8);
    short8 b0 = *(const short8*)gb, b1 = *(const short8*)(gb + 8);
    __syncthreads();
    *(short8*)&As[srow][sseg] = a0; *(short8*)&As[srow][sseg + 8] = a1;
    *(short8*)&Bs[srow][sseg] = b0; *(short8*)&Bs[srow][sseg + 8] = b1;
    __syncthreads();
    short8 af[4], bf[4];
#pragma unroll
    for (int m = 0; m < 4; m++) af[m] = *(const short8*)&As[wr * 64 + m * 16 + c][g * 8];
#pragma unroll
    for (int n = 0; n < 4; n++) bf[n] = *(const short8*)&Bs[wc * 64 + n * 16 + c][g * 8];
#pragma unroll
    for (int m = 0; m < 4; m++)
#pragma unroll
      for (int n = 0; n < 4; n++) acc[m][n] = mfma16(af[m], bf[n], acc[m][n]);
  }
  int colbase = bn + wc * 64;
#pragma unroll
  for (int m = 0; m < 4; m++) {
    int rowb = bm + wr * 64 + m * 16 + 4 * g;
#pragma unroll
    for (int e = 0; e < 4; e++) {
      int srw = rowb + e;
#pragma unroll
      for (int n = 0; n < 4; n++) {
        int col = colbase + n * 16 + c;
        out[(size_t)srw * EMB + col] = acc[m][n][e] + bias[col];
      }
    }
  }
}

// ---------------- launcher ----------------

extern "C" void kernel_launch(void* const* d_in, const int* in_sizes, int n_in,
                              void* d_out, int out_size, void* d_ws, size_t ws_size,
                              hipStream_t stream) {
  const float* x    = (const float*)d_in[0];
  // d_in[1] = causal mask (tril) — implemented analytically
  const float* Wqkv = (const float*)d_in[2];
  const float* bqkv = (const float*)d_in[3];
  const float* Wout = (const float*)d_in[4];
  const float* bout = (const float*)d_in[5];
  float* out = (float*)d_out;

  char* ws = (char*)d_ws;
  // bf16 workspace layout (bytes), all 16B-aligned
  u16* xb     = (u16*)(ws);                       // 4096*768
  u16* wqkvt  = (u16*)(ws + 6291456);             // 2304*768
  u16* woutt  = (u16*)(ws + 9830400);             // 768*768
  u16* Qb     = (u16*)(ws + 11010048);            // 12*4096*64
  u16* Kb     = (u16*)(ws + 17301504);
  u16* Vtb    = (u16*)(ws + 23592960);
  u16* Ob     = (u16*)(ws + 29884416);            // 4096*768
  // total 36175872 bytes

  k_conv_x<<<(S_LEN * EMB + 255) / 256, 256, 0, stream>>>(x, xb, S_LEN * EMB);
  k_transpose_w<<<(EMB * 3 * EMB + 255) / 256, 256, 0, stream>>>(Wqkv, wqkvt, EMB, 3 * EMB);
  k_transpose_w<<<(EMB * EMB + 255) / 256, 256, 0, stream>>>(Wout, woutt, EMB, EMB);

  k_qkv<<<dim3(32, 18), 256, 0, stream>>>(xb, wqkvt, bqkv, Qb, Kb, Vtb);
  k_attn<<<NH * 64, 256, 0, stream>>>(Qb, Kb, Vtb, Ob);
  k_out<<<dim3(32, 6), 256, 0, stream>>>(Ob, woutt, bout, out);
}

// Round 2
// 220.407 us; speedup vs baseline: 1.4615x; 1.4615x over previous
//
#include <hip/hip_runtime.h>

typedef unsigned short u16;
typedef unsigned int   u32;
using short8 = __attribute__((ext_vector_type(8))) short;
using f32x4  = __attribute__((ext_vector_type(4))) float;
using f32x16 = __attribute__((ext_vector_type(16))) float;
using u32x4  = __attribute__((ext_vector_type(4))) unsigned int;

#define S_LEN 4096
#define EMB   768
#define NH    12
#define DH    64

// 0.125 (=1/sqrt(64)) * log2(e): folded into Q so softmax uses exp2 directly
#define QSCALE 0.18033688011112042f

__device__ __forceinline__ u16 f2bf(float f) {
  unsigned int u = __builtin_bit_cast(unsigned int, f);
  u += 0x7fffu + ((u >> 16) & 1u);
  return (u16)(u >> 16);
}

__device__ __forceinline__ u32 cvtpk(float lo, float hi) {
  u32 r;
  asm("v_cvt_pk_bf16_f32 %0, %1, %2" : "=v"(r) : "v"(lo), "v"(hi));
  return r;
}

__device__ __forceinline__ float fexp2(float x) {
#if __has_builtin(__builtin_amdgcn_exp2f)
  return __builtin_amdgcn_exp2f(x);
#else
  return exp2f(x);
#endif
}

__device__ __forceinline__ f32x4 mfma16(short8 a, short8 b, f32x4 c) {
  return __builtin_amdgcn_mfma_f32_16x16x32_bf16(a, b, c, 0, 0, 0);
}
__device__ __forceinline__ f32x16 mfma32(short8 a, short8 b, f32x16 c) {
  return __builtin_amdgcn_mfma_f32_32x32x16_bf16(a, b, c, 0, 0, 0);
}

// ---------------- conversion / transpose kernels ----------------

__global__ void k_conv_x(const float* __restrict__ x, u16* __restrict__ xb, int n) {
  int i = blockIdx.x * 256 + threadIdx.x;
  if (i < n) xb[i] = f2bf(x[i]);
}

__global__ void k_transpose_w(const float* __restrict__ w, u16* __restrict__ wt,
                              int rows, int cols) {
  int i = blockIdx.x * 256 + threadIdx.x;
  if (i < rows * cols) {
    int n = i / rows, k = i - n * rows;
    wt[i] = f2bf(w[(size_t)k * cols + n]);
  }
}

// ---------------- QKV GEMM + bias + RoPE epilogue ----------------
__global__ __launch_bounds__(256) void k_qkv(const u16* __restrict__ A,
                                             const u16* __restrict__ Bt,
                                             const float* __restrict__ bias,
                                             u16* __restrict__ Qb,
                                             u16* __restrict__ Kb,
                                             u16* __restrict__ Vt) {
  __shared__ u16 As[128][40];
  __shared__ u16 Bs[128][40];
  int t = threadIdx.x;
  int w = t >> 6, lane = t & 63, g = lane >> 4, c = lane & 15;
  int wr = w >> 1, wc = w & 1;
  int bm = blockIdx.x * 128, bn = blockIdx.y * 128;

  f32x4 acc[4][4];
#pragma unroll
  for (int m = 0; m < 4; m++)
#pragma unroll
    for (int n = 0; n < 4; n++) acc[m][n] = (f32x4){0.f, 0.f, 0.f, 0.f};

  int srow = t >> 1, sseg = (t & 1) * 16;
  for (int bk = 0; bk < EMB; bk += 32) {
    const u16* ga = A  + (size_t)(bm + srow) * EMB + bk + sseg;
    const u16* gb = Bt + (size_t)(bn + srow) * EMB + bk + sseg;
    short8 a0 = *(const short8*)ga, a1 = *(const short8*)(ga + 8);
    short8 b0 = *(const short8*)gb, b1 = *(const short8*)(gb + 8);
    __syncthreads();
    *(short8*)&As[srow][sseg] = a0; *(short8*)&As[srow][sseg + 8] = a1;
    *(short8*)&Bs[srow][sseg] = b0; *(short8*)&Bs[srow][sseg + 8] = b1;
    __syncthreads();
    short8 af[4], bf[4];
#pragma unroll
    for (int m = 0; m < 4; m++) af[m] = *(const short8*)&As[wr * 64 + m * 16 + c][g * 8];
#pragma unroll
    for (int n = 0; n < 4; n++) bf[n] = *(const short8*)&Bs[wc * 64 + n * 16 + c][g * 8];
#pragma unroll
    for (int m = 0; m < 4; m++)
#pragma unroll
      for (int n = 0; n < 4; n++) acc[m][n] = mfma16(af[m], bf[n], acc[m][n]);
  }

  int colbase = bn + wc * 64;
  int sec = colbase / EMB;               // 0=Q 1=K 2=V
  int hh  = (colbase % EMB) / DH;
  float qs = (sec == 0) ? QSCALE : 1.0f;
  float invf[2];
#pragma unroll
  for (int n = 0; n < 2; n++) {
    int d1 = n * 16 + c;
    invf[n] = exp2f(-(float)d1 * (13.287712379549449f / 32.0f));
  }
#pragma unroll
  for (int m = 0; m < 4; m++) {
    int rowb = bm + wr * 64 + m * 16 + 4 * g;
#pragma unroll
    for (int e = 0; e < 4; e++) {
      int srw = rowb + e;
      float v[4];
#pragma unroll
      for (int n = 0; n < 4; n++) v[n] = acc[m][n][e] + bias[colbase + n * 16 + c];
      if (sec == 2) {
#pragma unroll
        for (int n = 0; n < 4; n++)
          Vt[(size_t)(hh * DH + n * 16 + c) * S_LEN + srw] = f2bf(v[n]);
      } else {
        u16* dst = (sec == 0) ? Qb : Kb;
        size_t base = ((size_t)hh * S_LEN + srw) * DH;
#pragma unroll
        for (int n = 0; n < 2; n++) {
          int d1 = n * 16 + c;
          float ang = (float)srw * invf[n];
          float sn, cs;
          sincosf(ang, &sn, &cs);
          float o1 = (v[n] * cs - v[n + 2] * sn) * qs;
          float o2 = (v[n + 2] * cs + v[n] * sn) * qs;
          dst[base + d1]      = f2bf(o1);
          dst[base + d1 + 32] = f2bf(o2);
        }
      }
    }
  }
}

// ---------------- flash attention (swapped-operand, LDS-free) ----------------
// Q,K: [H][S][64] bf16 (Q pre-scaled by QSCALE); Vt: [H][64][S] bf16; O: [S][768] bf16
// 1 wave per 32 q-rows. QK^T computed transposed: lane owns one q-row.
// acc = O^T tiles: lane = q-col, regs = d-rows -> softmax stats stay lane-local.

template<bool MASKED>
__device__ __forceinline__ void attn_tile(int kv0, int qi, int half,
    const u16* __restrict__ Kh, const u16* __restrict__ Vh,
    short8 qf0, short8 qf1, short8 qf2, short8 qf3,
    f32x16& acc0, f32x16& acc1, float& m, float& l) {
  const u16* kp = Kh + (size_t)(kv0 + qi) * DH + half * 8;
  short8 k0 = *(const short8*)(kp);
  short8 k1 = *(const short8*)(kp + 16);
  short8 k2 = *(const short8*)(kp + 32);
  short8 k3 = *(const short8*)(kp + 48);
  f32x16 sc = {0,0,0,0,0,0,0,0,0,0,0,0,0,0,0,0};
  sc = mfma32(k0, qf0, sc);
  sc = mfma32(k1, qf1, sc);
  sc = mfma32(k2, qf2, sc);
  sc = mfma32(k3, qf3, sc);
  if (MASKED) {
#pragma unroll
    for (int i = 0; i < 16; i++) {
      int kl = (i & 3) + 8 * (i >> 2) + 4 * half;
      if (kl > qi) sc[i] = -1e30f;
    }
  }
  // row max (16 in-register + one cross-half exchange)
  float t0 = fmaxf(fmaxf(sc[0], sc[1]), fmaxf(sc[2], sc[3]));
  float t1 = fmaxf(fmaxf(sc[4], sc[5]), fmaxf(sc[6], sc[7]));
  float t2 = fmaxf(fmaxf(sc[8], sc[9]), fmaxf(sc[10], sc[11]));
  float t3 = fmaxf(fmaxf(sc[12], sc[13]), fmaxf(sc[14], sc[15]));
  float pmax = fmaxf(fmaxf(t0, t1), fmaxf(t2, t3));
  float rmax = fmaxf(pmax, __shfl_xor(pmax, 32));
  // defer-max (T13): only rescale when row max grew past threshold
  if (__any(rmax > m + 8.0f)) {
    float mn = fmaxf(m, rmax);
    float f = fexp2(m - mn);
    m = mn; l *= f;
#pragma unroll
    for (int i = 0; i < 16; i++) { acc0[i] *= f; acc1[i] *= f; }
  }
  f32x16 p;
#pragma unroll
  for (int i = 0; i < 16; i++) p[i] = fexp2(sc[i] - m);
  l += ((p[0] + p[1]) + (p[2] + p[3])) + ((p[4] + p[5]) + (p[6] + p[7]))
     + ((p[8] + p[9]) + (p[10] + p[11])) + ((p[12] + p[13]) + (p[14] + p[15]));
  // pack P to bf16 B-frags (lane = q-col, elements = k): cross-half exchange
  u32 w0 = cvtpk(p[0], p[1]),  w1 = cvtpk(p[2], p[3]);
  u32 w2 = cvtpk(p[4], p[5]),  w3 = cvtpk(p[6], p[7]);
  u32 w4 = cvtpk(p[8], p[9]),  w5 = cvtpk(p[10], p[11]);
  u32 w6 = cvtpk(p[12], p[13]), w7 = cvtpk(p[14], p[15]);
  u32 x0 = (u32)__shfl_xor((int)w0, 32), x1 = (u32)__shfl_xor((int)w1, 32);
  u32 x2 = (u32)__shfl_xor((int)w2, 32), x3 = (u32)__shfl_xor((int)w3, 32);
  u32 x4 = (u32)__shfl_xor((int)w4, 32), x5 = (u32)__shfl_xor((int)w5, 32);
  u32 x6 = (u32)__shfl_xor((int)w6, 32), x7 = (u32)__shfl_xor((int)w7, 32);
  bool hi = (half != 0);
  u32x4 f0 = { hi ? x2 : w0, hi ? x3 : w1, hi ? w2 : x0, hi ? w3 : x1 };
  u32x4 f1 = { hi ? x6 : w4, hi ? x7 : w5, hi ? w6 : x4, hi ? w7 : x5 };
  short8 pa0 = __builtin_bit_cast(short8, f0);
  short8 pa1 = __builtin_bit_cast(short8, f1);
  // PV transposed: acc = V^T * P^T -> O^T, lane = q
  const u16* vp = Vh + (size_t)qi * S_LEN + kv0 + half * 8;
  short8 v00 = *(const short8*)(vp);
  short8 v01 = *(const short8*)(vp + 16);
  short8 v10 = *(const short8*)(vp + (size_t)32 * S_LEN);
  short8 v11 = *(const short8*)(vp + (size_t)32 * S_LEN + 16);
  acc0 = mfma32(v00, pa0, acc0);
  acc0 = mfma32(v01, pa1, acc0);
  acc1 = mfma32(v10, pa0, acc1);
  acc1 = mfma32(v11, pa1, acc1);
}

__global__ __launch_bounds__(64) void k_attn(const u16* __restrict__ Q,
                                             const u16* __restrict__ K,
                                             const u16* __restrict__ Vt,
                                             u16* __restrict__ O) {
  int lane = threadIdx.x;
  int qi = lane & 31, half = lane >> 5;
  int b = blockIdx.x;
  int h = b % NH;
  int qb = 127 - b / NH;              // longest blocks dispatched first

  const u16* Qh = Q  + (size_t)h * S_LEN * DH;
  const u16* Kh = K  + (size_t)h * S_LEN * DH;
  const u16* Vh = Vt + (size_t)h * DH * S_LEN;

  const u16* qp = Qh + (size_t)(qb * 32 + qi) * DH + half * 8;
  short8 qf0 = *(const short8*)(qp);
  short8 qf1 = *(const short8*)(qp + 16);
  short8 qf2 = *(const short8*)(qp + 32);
  short8 qf3 = *(const short8*)(qp + 48);

  f32x16 acc0 = {0,0,0,0,0,0,0,0,0,0,0,0,0,0,0,0};
  f32x16 acc1 = {0,0,0,0,0,0,0,0,0,0,0,0,0,0,0,0};
  float m = -1e30f, l = 0.f;

  int kvend = qb * 32;
  for (int kv0 = 0; kv0 < kvend; kv0 += 32)
    attn_tile<false>(kv0, qi, half, Kh, Vh, qf0, qf1, qf2, qf3, acc0, acc1, m, l);
  attn_tile<true>(kvend, qi, half, Kh, Vh, qf0, qf1, qf2, qf3, acc0, acc1, m, l);

  float lrow = l + __shfl_xor(l, 32);
  float rl = 1.0f / lrow;
  u16* orow = O + (size_t)(qb * 32 + qi) * EMB + h * DH;
#pragma unroll
  for (int i = 0; i < 16; i += 2) {
    int dl = (i & 3) + 8 * (i >> 2) + 4 * half;
    u32 wa = cvtpk(acc0[i] * rl, acc0[i + 1] * rl);
    u32 wb = cvtpk(acc1[i] * rl, acc1[i + 1] * rl);
    *(u32*)(orow + dl)      = wa;
    *(u32*)(orow + 32 + dl) = wb;
  }
}

// ---------------- output projection ----------------
__global__ __launch_bounds__(256) void k_out(const u16* __restrict__ A,
                                             const u16* __restrict__ Bt,
                                             const float* __restrict__ bias,
                                             float* __restrict__ out) {
  __shared__ u16 As[128][40];
  __shared__ u16 Bs[128][40];
  int t = threadIdx.x;
  int w = t >> 6, lane = t & 63, g = lane >> 4, c = lane & 15;
  int wr = w >> 1, wc = w & 1;
  int bm = blockIdx.x * 128, bn = blockIdx.y * 128;

  f32x4 acc[4][4];
#pragma unroll
  for (int m = 0; m < 4; m++)
#pragma unroll
    for (int n = 0; n < 4; n++) acc[m][n] = (f32x4){0.f, 0.f, 0.f, 0.f};

  int srow = t >> 1, sseg = (t & 1) * 16;
  for (int bk = 0; bk < EMB; bk += 32) {
    const u16* ga = A  + (size_t)(bm + srow) * EMB + bk + sseg;
    const u16* gb = Bt + (size_t)(bn + srow) * EMB + bk + sseg;
    short8 a0 = *(const short8*)ga, a1 = *(const short8*)(ga + 8);
    short8 b0 = *(const short8*)gb, b1 = *(const short8*)(gb + 8);
    __syncthreads();
    *(short8*)&As[srow][sseg] = a0; *(short8*)&As[srow][sseg + 8] = a1;
    *(short8*)&Bs[srow][sseg] = b0; *(short8*)&Bs[srow][sseg + 8] = b1;
    __syncthreads();
    short8 af[4], bf[4];
#pragma unroll
    for (int m = 0; m < 4; m++) af[m] = *(const short8*)&As[wr * 64 + m * 16 + c][g * 8];
#pragma unroll
    for (int n = 0; n < 4; n++) bf[n] = *(const short8*)&Bs[wc * 64 + n * 16 + c][g * 8];
#pragma unroll
    for (int m = 0; m < 4; m++)
#pragma unroll
      for (int n = 0; n < 4; n++) acc[m][n] = mfma16(af[m], bf[n], acc[m][n]);
  }
  int colbase = bn + wc * 64;
#pragma unroll
  for (int m = 0; m < 4; m++) {
    int rowb = bm + wr * 64 + m * 16 + 4 * g;
#pragma unroll
    for (int e = 0; e < 4; e++) {
      int srw = rowb + e;
#pragma unroll
      for (int n = 0; n < 4; n++) {
        int col = colbase + n * 16 + c;
        out[(size_t)srw * EMB + col] = acc[m][n][e] + bias[col];
      }
    }
  }
}

// ---------------- launcher ----------------

extern "C" void kernel_launch(void* const* d_in, const int* in_sizes, int n_in,
                              void* d_out, int out_size, void* d_ws, size_t ws_size,
                              hipStream_t stream) {
  const float* x    = (const float*)d_in[0];
  const float* Wqkv = (const float*)d_in[2];
  const float* bqkv = (const float*)d_in[3];
  const float* Wout = (const float*)d_in[4];
  const float* bout = (const float*)d_in[5];
  float* out = (float*)d_out;

  char* ws = (char*)d_ws;
  u16* xb     = (u16*)(ws);
  u16* wqkvt  = (u16*)(ws + 6291456);
  u16* woutt  = (u16*)(ws + 9830400);
  u16* Qb     = (u16*)(ws + 11010048);
  u16* Kb     = (u16*)(ws + 17301504);
  u16* Vtb    = (u16*)(ws + 23592960);
  u16* Ob     = (u16*)(ws + 29884416);

  k_conv_x<<<(S_LEN * EMB + 255) / 256, 256, 0, stream>>>(x, xb, S_LEN * EMB);
  k_transpose_w<<<(EMB * 3 * EMB + 255) / 256, 256, 0, stream>>>(Wqkv, wqkvt, EMB, 3 * EMB);
  k_transpose_w<<<(EMB * EMB + 255) / 256, 256, 0, stream>>>(Wout, woutt, EMB, EMB);

  k_qkv<<<dim3(32, 18), 256, 0, stream>>>(xb, wqkvt, bqkv, Qb, Kb, Vtb);
  k_attn<<<NH * 128, 64, 0, stream>>>(Qb, Kb, Vtb, Ob);
  k_out<<<dim3(32, 6), 256, 0, stream>>>(Ob, woutt, bout, out);
}

// Round 3
// 180.591 us; speedup vs baseline: 1.7838x; 1.2205x over previous
//
#include <hip/hip_runtime.h>

typedef unsigned short u16;
typedef unsigned int   u32;
using short8 = __attribute__((ext_vector_type(8))) short;
using f32x4  = __attribute__((ext_vector_type(4))) float;
using f32x16 = __attribute__((ext_vector_type(16))) float;
using u32x4  = __attribute__((ext_vector_type(4))) unsigned int;

#define S_LEN 4096
#define EMB   768
#define NH    12
#define DH    64

// 0.125 (=1/sqrt(64)) * log2(e): folded into Q so softmax uses exp2 directly
#define QSCALE 0.18033688011112042f

__device__ __forceinline__ u16 f2bf(float f) {
  unsigned int u = __builtin_bit_cast(unsigned int, f);
  u += 0x7fffu + ((u >> 16) & 1u);
  return (u16)(u >> 16);
}

__device__ __forceinline__ u32 cvtpk(float lo, float hi) {
  u32 r;
  asm("v_cvt_pk_bf16_f32 %0, %1, %2" : "=v"(r) : "v"(lo), "v"(hi));
  return r;
}

__device__ __forceinline__ float fexp2(float x) {
#if __has_builtin(__builtin_amdgcn_exp2f)
  return __builtin_amdgcn_exp2f(x);
#else
  return exp2f(x);
#endif
}

__device__ __forceinline__ f32x4 mfma16(short8 a, short8 b, f32x4 c) {
  return __builtin_amdgcn_mfma_f32_16x16x32_bf16(a, b, c, 0, 0, 0);
}
__device__ __forceinline__ f32x16 mfma32(short8 a, short8 b, f32x16 c) {
  return __builtin_amdgcn_mfma_f32_32x32x16_bf16(a, b, c, 0, 0, 0);
}

// ---------------- conversion / transpose kernels ----------------

__global__ void k_conv_x(const float* __restrict__ x, u16* __restrict__ xb, int n) {
  int i = blockIdx.x * 256 + threadIdx.x;
  if (i < n) xb[i] = f2bf(x[i]);
}

// Tiled transpose+convert: wt[n][k] = bf16(w[k][n]); w [rows=K][cols=N]
__global__ __launch_bounds__(256) void k_transpose_w(const float* __restrict__ w,
                                                     u16* __restrict__ wt,
                                                     int rows, int cols) {
  __shared__ float tile[32][33];
  int tx = threadIdx.x & 31, ty = threadIdx.x >> 5;
  int kb = blockIdx.x * 32;   // K base
  int nb = blockIdx.y * 32;   // N base
#pragma unroll
  for (int j = 0; j < 4; j++)
    tile[ty + 8 * j][tx] = w[(size_t)(kb + ty + 8 * j) * cols + nb + tx];
  __syncthreads();
#pragma unroll
  for (int j = 0; j < 4; j++)
    wt[(size_t)(nb + ty + 8 * j) * rows + kb + tx] = f2bf(tile[tx][ty + 8 * j]);
}

// ---------------- QKV GEMM + bias + RoPE epilogue ----------------
__global__ __launch_bounds__(256) void k_qkv(const u16* __restrict__ A,
                                             const u16* __restrict__ Bt,
                                             const float* __restrict__ bias,
                                             u16* __restrict__ Qb,
                                             u16* __restrict__ Kb,
                                             u16* __restrict__ Vt) {
  __shared__ u16 As[128][40];
  __shared__ u16 Bs[128][40];
  int t = threadIdx.x;
  int w = t >> 6, lane = t & 63, g = lane >> 4, c = lane & 15;
  int wr = w >> 1, wc = w & 1;
  int bm = blockIdx.x * 128, bn = blockIdx.y * 128;

  f32x4 acc[4][4];
#pragma unroll
  for (int m = 0; m < 4; m++)
#pragma unroll
    for (int n = 0; n < 4; n++) acc[m][n] = (f32x4){0.f, 0.f, 0.f, 0.f};

  int srow = t >> 1, sseg = (t & 1) * 16;
  for (int bk = 0; bk < EMB; bk += 32) {
    const u16* ga = A  + (size_t)(bm + srow) * EMB + bk + sseg;
    const u16* gb = Bt + (size_t)(bn + srow) * EMB + bk + sseg;
    short8 a0 = *(const short8*)ga, a1 = *(const short8*)(ga + 8);
    short8 b0 = *(const short8*)gb, b1 = *(const short8*)(gb + 8);
    __syncthreads();
    *(short8*)&As[srow][sseg] = a0; *(short8*)&As[srow][sseg + 8] = a1;
    *(short8*)&Bs[srow][sseg] = b0; *(short8*)&Bs[srow][sseg + 8] = b1;
    __syncthreads();
    short8 af[4], bf[4];
#pragma unroll
    for (int m = 0; m < 4; m++) af[m] = *(const short8*)&As[wr * 64 + m * 16 + c][g * 8];
#pragma unroll
    for (int n = 0; n < 4; n++) bf[n] = *(const short8*)&Bs[wc * 64 + n * 16 + c][g * 8];
#pragma unroll
    for (int m = 0; m < 4; m++)
#pragma unroll
      for (int n = 0; n < 4; n++) acc[m][n] = mfma16(af[m], bf[n], acc[m][n]);
  }

  int colbase = bn + wc * 64;
  int sec = colbase / EMB;               // 0=Q 1=K 2=V
  int hh  = (colbase % EMB) / DH;
  float qs = (sec == 0) ? QSCALE : 1.0f;
  float invf[2];
#pragma unroll
  for (int n = 0; n < 2; n++) {
    int d1 = n * 16 + c;
    invf[n] = exp2f(-(float)d1 * (13.287712379549449f / 32.0f));
  }
#pragma unroll
  for (int m = 0; m < 4; m++) {
    int rowb = bm + wr * 64 + m * 16 + 4 * g;
#pragma unroll
    for (int e = 0; e < 4; e++) {
      int srw = rowb + e;
      float v[4];
#pragma unroll
      for (int n = 0; n < 4; n++) v[n] = acc[m][n][e] + bias[colbase + n * 16 + c];
      if (sec == 2) {
#pragma unroll
        for (int n = 0; n < 4; n++)
          Vt[(size_t)(hh * DH + n * 16 + c) * S_LEN + srw] = f2bf(v[n]);
      } else {
        u16* dst = (sec == 0) ? Qb : Kb;
        size_t base = ((size_t)hh * S_LEN + srw) * DH;
#pragma unroll
        for (int n = 0; n < 2; n++) {
          int d1 = n * 16 + c;
          float ang = (float)srw * invf[n];
          float sn, cs;
          sincosf(ang, &sn, &cs);
          float o1 = (v[n] * cs - v[n + 2] * sn) * qs;
          float o2 = (v[n + 2] * cs + v[n] * sn) * qs;
          dst[base + d1]      = f2bf(o1);
          dst[base + d1 + 32] = f2bf(o2);
        }
      }
    }
  }
}

// ---------------- flash attention (swapped-operand, 4-wave KV-split) ----------------
// Q,K: [H][S][64] bf16 (Q pre-scaled); Vt: [H][64][S] bf16; O: [S][768] bf16
// Block = 4 waves over one 32-row Q block; each wave takes a contiguous quarter
// of the KV tiles with private (m,l,acc); merged via LDS at the end.

template<bool MASKED>
__device__ __forceinline__ void attn_tile(int kv0, int qi, int half,
    const u16* __restrict__ Kh, const u16* __restrict__ Vh,
    short8 qf0, short8 qf1, short8 qf2, short8 qf3,
    f32x16& acc0, f32x16& acc1, float& m, float& l) {
  const u16* kp = Kh + (size_t)(kv0 + qi) * DH + half * 8;
  short8 k0 = *(const short8*)(kp);
  short8 k1 = *(const short8*)(kp + 16);
  short8 k2 = *(const short8*)(kp + 32);
  short8 k3 = *(const short8*)(kp + 48);
  f32x16 sc = {0,0,0,0,0,0,0,0,0,0,0,0,0,0,0,0};
  sc = mfma32(k0, qf0, sc);
  sc = mfma32(k1, qf1, sc);
  sc = mfma32(k2, qf2, sc);
  sc = mfma32(k3, qf3, sc);
  if (MASKED) {
#pragma unroll
    for (int i = 0; i < 16; i++) {
      int kl = (i & 3) + 8 * (i >> 2) + 4 * half;
      if (kl > qi) sc[i] = -1e30f;
    }
  }
  float t0 = fmaxf(fmaxf(sc[0], sc[1]), fmaxf(sc[2], sc[3]));
  float t1 = fmaxf(fmaxf(sc[4], sc[5]), fmaxf(sc[6], sc[7]));
  float t2 = fmaxf(fmaxf(sc[8], sc[9]), fmaxf(sc[10], sc[11]));
  float t3 = fmaxf(fmaxf(sc[12], sc[13]), fmaxf(sc[14], sc[15]));
  float pmax = fmaxf(fmaxf(t0, t1), fmaxf(t2, t3));
  float rmax = fmaxf(pmax, __shfl_xor(pmax, 32));
  if (__any(rmax > m + 8.0f)) {
    float mn = fmaxf(m, rmax);
    float f = fexp2(m - mn);
    m = mn; l *= f;
#pragma unroll
    for (int i = 0; i < 16; i++) { acc0[i] *= f; acc1[i] *= f; }
  }
  f32x16 p;
#pragma unroll
  for (int i = 0; i < 16; i++) p[i] = fexp2(sc[i] - m);
  l += ((p[0] + p[1]) + (p[2] + p[3])) + ((p[4] + p[5]) + (p[6] + p[7]))
     + ((p[8] + p[9]) + (p[10] + p[11])) + ((p[12] + p[13]) + (p[14] + p[15]));
  u32 w0 = cvtpk(p[0], p[1]),  w1 = cvtpk(p[2], p[3]);
  u32 w2 = cvtpk(p[4], p[5]),  w3 = cvtpk(p[6], p[7]);
  u32 w4 = cvtpk(p[8], p[9]),  w5 = cvtpk(p[10], p[11]);
  u32 w6 = cvtpk(p[12], p[13]), w7 = cvtpk(p[14], p[15]);
  u32 x0 = (u32)__shfl_xor((int)w0, 32), x1 = (u32)__shfl_xor((int)w1, 32);
  u32 x2 = (u32)__shfl_xor((int)w2, 32), x3 = (u32)__shfl_xor((int)w3, 32);
  u32 x4 = (u32)__shfl_xor((int)w4, 32), x5 = (u32)__shfl_xor((int)w5, 32);
  u32 x6 = (u32)__shfl_xor((int)w6, 32), x7 = (u32)__shfl_xor((int)w7, 32);
  bool hi = (half != 0);
  u32x4 f0 = { hi ? x2 : w0, hi ? x3 : w1, hi ? w2 : x0, hi ? w3 : x1 };
  u32x4 f1 = { hi ? x6 : w4, hi ? x7 : w5, hi ? w6 : x4, hi ? w7 : x5 };
  short8 pa0 = __builtin_bit_cast(short8, f0);
  short8 pa1 = __builtin_bit_cast(short8, f1);
  const u16* vp = Vh + (size_t)qi * S_LEN + kv0 + half * 8;
  short8 v00 = *(const short8*)(vp);
  short8 v01 = *(const short8*)(vp + 16);
  short8 v10 = *(const short8*)(vp + (size_t)32 * S_LEN);
  short8 v11 = *(const short8*)(vp + (size_t)32 * S_LEN + 16);
  acc0 = mfma32(v00, pa0, acc0);
  acc0 = mfma32(v01, pa1, acc0);
  acc1 = mfma32(v10, pa0, acc1);
  acc1 = mfma32(v11, pa1, acc1);
}

__global__ __launch_bounds__(256, 4) void k_attn(const u16* __restrict__ Q,
                                                 const u16* __restrict__ K,
                                                 const u16* __restrict__ Vt,
                                                 u16* __restrict__ O) {
  __shared__ float Lacc[3][64][33];
  __shared__ float Lml[2][3][32];

  int t = threadIdx.x;
  int w = t >> 6, lane = t & 63;
  int qi = lane & 31, half = lane >> 5;
  int b = blockIdx.x;
  int h = b % NH;
  int qb = 127 - b / NH;              // longest blocks first

  const u16* Qh = Q  + (size_t)h * S_LEN * DH;
  const u16* Kh = K  + (size_t)h * S_LEN * DH;
  const u16* Vh = Vt + (size_t)h * DH * S_LEN;

  const u16* qp = Qh + (size_t)(qb * 32 + qi) * DH + half * 8;
  short8 qf0 = *(const short8*)(qp);
  short8 qf1 = *(const short8*)(qp + 16);
  short8 qf2 = *(const short8*)(qp + 32);
  short8 qf3 = *(const short8*)(qp + 48);

  f32x16 acc0 = {0,0,0,0,0,0,0,0,0,0,0,0,0,0,0,0};
  f32x16 acc1 = {0,0,0,0,0,0,0,0,0,0,0,0,0,0,0,0};
  float m = -1e30f, l = 0.f;

  int nt = qb + 1;                     // total KV tiles (last one masked)
  int ck = (nt + 3) >> 2;              // tiles per wave
  int start = w * ck;
  int end   = min(start + ck, nt);
  int endu  = min(end, nt - 1);        // unmasked range end
  for (int tt = start; tt < endu; tt++)
    attn_tile<false>(tt * 32, qi, half, Kh, Vh, qf0, qf1, qf2, qf3, acc0, acc1, m, l);
  if (start < nt && end == nt)
    attn_tile<true>((nt - 1) * 32, qi, half, Kh, Vh, qf0, qf1, qf2, qf3, acc0, acc1, m, l);

  // cross-wave merge
  float l2 = l + __shfl_xor(l, 32);    // combine halves' partial sums
  if (w > 0) {
#pragma unroll
    for (int i = 0; i < 16; i++) {
      Lacc[w - 1][lane][i]      = acc0[i];
      Lacc[w - 1][lane][16 + i] = acc1[i];
    }
    if (half == 0) { Lml[0][w - 1][qi] = m; Lml[1][w - 1][qi] = l2; }
  }
  __syncthreads();
  if (w == 0) {
    float mw[3], lw[3];
    float M = m;
#pragma unroll
    for (int j = 0; j < 3; j++) { mw[j] = Lml[0][j][qi]; lw[j] = Lml[1][j][qi]; M = fmaxf(M, mw[j]); }
    float f0 = fexp2(m - M);
    float ltot = l2 * f0;
#pragma unroll
    for (int i = 0; i < 16; i++) { acc0[i] *= f0; acc1[i] *= f0; }
#pragma unroll
    for (int j = 0; j < 3; j++) {
      float fj = fexp2(mw[j] - M);
      ltot += lw[j] * fj;
#pragma unroll
      for (int i = 0; i < 16; i++) {
        acc0[i] += fj * Lacc[j][lane][i];
        acc1[i] += fj * Lacc[j][lane][16 + i];
      }
    }
    float rl = 1.0f / ltot;
    u16* orow = O + (size_t)(qb * 32 + qi) * EMB + h * DH;
#pragma unroll
    for (int i = 0; i < 16; i += 2) {
      int dl = (i & 3) + 8 * (i >> 2) + 4 * half;
      u32 wa = cvtpk(acc0[i] * rl, acc0[i + 1] * rl);
      u32 wb = cvtpk(acc1[i] * rl, acc1[i + 1] * rl);
      *(u32*)(orow + dl)      = wa;
      *(u32*)(orow + 32 + dl) = wb;
    }
  }
}

// ---------------- output projection ----------------
__global__ __launch_bounds__(256) void k_out(const u16* __restrict__ A,
                                             const u16* __restrict__ Bt,
                                             const float* __restrict__ bias,
                                             float* __restrict__ out) {
  __shared__ u16 As[128][40];
  __shared__ u16 Bs[128][40];
  int t = threadIdx.x;
  int w = t >> 6, lane = t & 63, g = lane >> 4, c = lane & 15;
  int wr = w >> 1, wc = w & 1;
  int bm = blockIdx.x * 128, bn = blockIdx.y * 128;

  f32x4 acc[4][4];
#pragma unroll
  for (int m = 0; m < 4; m++)
#pragma unroll
    for (int n = 0; n < 4; n++) acc[m][n] = (f32x4){0.f, 0.f, 0.f, 0.f};

  int srow = t >> 1, sseg = (t & 1) * 16;
  for (int bk = 0; bk < EMB; bk += 32) {
    const u16* ga = A  + (size_t)(bm + srow) * EMB + bk + sseg;
    const u16* gb = Bt + (size_t)(bn + srow) * EMB + bk + sseg;
    short8 a0 = *(const short8*)ga, a1 = *(const short8*)(ga + 8);
    short8 b0 = *(const short8*)gb, b1 = *(const short8*)(gb + 8);
    __syncthreads();
    *(short8*)&As[srow][sseg] = a0; *(short8*)&As[srow][sseg + 8] = a1;
    *(short8*)&Bs[srow][sseg] = b0; *(short8*)&Bs[srow][sseg + 8] = b1;
    __syncthreads();
    short8 af[4], bf[4];
#pragma unroll
    for (int m = 0; m < 4; m++) af[m] = *(const short8*)&As[wr * 64 + m * 16 + c][g * 8];
#pragma unroll
    for (int n = 0; n < 4; n++) bf[n] = *(const short8*)&Bs[wc * 64 + n * 16 + c][g * 8];
#pragma unroll
    for (int m = 0; m < 4; m++)
#pragma unroll
      for (int n = 0; n < 4; n++) acc[m][n] = mfma16(af[m], bf[n], acc[m][n]);
  }
  int colbase = bn + wc * 64;
#pragma unroll
  for (int m = 0; m < 4; m++) {
    int rowb = bm + wr * 64 + m * 16 + 4 * g;
#pragma unroll
    for (int e = 0; e < 4; e++) {
      int srw = rowb + e;
#pragma unroll
      for (int n = 0; n < 4; n++) {
        int col = colbase + n * 16 + c;
        out[(size_t)srw * EMB + col] = acc[m][n][e] + bias[col];
      }
    }
  }
}

// ---------------- launcher ----------------

extern "C" void kernel_launch(void* const* d_in, const int* in_sizes, int n_in,
                              void* d_out, int out_size, void* d_ws, size_t ws_size,
                              hipStream_t stream) {
  const float* x    = (const float*)d_in[0];
  const float* Wqkv = (const float*)d_in[2];
  const float* bqkv = (const float*)d_in[3];
  const float* Wout = (const float*)d_in[4];
  const float* bout = (const float*)d_in[5];
  float* out = (float*)d_out;

  char* ws = (char*)d_ws;
  u16* xb     = (u16*)(ws);
  u16* wqkvt  = (u16*)(ws + 6291456);
  u16* woutt  = (u16*)(ws + 9830400);
  u16* Qb     = (u16*)(ws + 11010048);
  u16* Kb     = (u16*)(ws + 17301504);
  u16* Vtb    = (u16*)(ws + 23592960);
  u16* Ob     = (u16*)(ws + 29884416);

  k_conv_x<<<(S_LEN * EMB + 255) / 256, 256, 0, stream>>>(x, xb, S_LEN * EMB);
  k_transpose_w<<<dim3(EMB / 32, 3 * EMB / 32), 256, 0, stream>>>(Wqkv, wqkvt, EMB, 3 * EMB);
  k_transpose_w<<<dim3(EMB / 32, EMB / 32), 256, 0, stream>>>(Wout, woutt, EMB, EMB);

  k_qkv<<<dim3(32, 18), 256, 0, stream>>>(xb, wqkvt, bqkv, Qb, Kb, Vtb);
  k_attn<<<NH * 128, 256, 0, stream>>>(Qb, Kb, Vtb, Ob);
  k_out<<<dim3(32, 6), 256, 0, stream>>>(Ob, woutt, bout, out);
}

// Round 6
// 178.175 us; speedup vs baseline: 1.8080x; 1.0136x over previous
//
#include <hip/hip_runtime.h>

typedef unsigned short u16;
typedef unsigned int   u32;
using short8 = __attribute__((ext_vector_type(8))) short;
using f32x4  = __attribute__((ext_vector_type(4))) float;
using f32x16 = __attribute__((ext_vector_type(16))) float;
using u32x4  = __attribute__((ext_vector_type(4))) unsigned int;

#define S_LEN 4096
#define EMB   768
#define NH    12
#define DH    64

// 0.125 (=1/sqrt(64)) * log2(e): folded into Q so softmax uses exp2 directly
#define QSCALE 0.18033688011112042f

__device__ __forceinline__ u16 f2bf(float f) {
  unsigned int u = __builtin_bit_cast(unsigned int, f);
  u += 0x7fffu + ((u >> 16) & 1u);
  return (u16)(u >> 16);
}

__device__ __forceinline__ u32 cvtpk(float lo, float hi) {
  u32 r;
  asm("v_cvt_pk_bf16_f32 %0, %1, %2" : "=v"(r) : "v"(lo), "v"(hi));
  return r;
}

// Cross-half (lane ^ 32) combines -- PROVEN primitive (R3 passed with these).
// Raw v_permlane32_swap asm failed both orientations (R4/R5); do not use.
__device__ __forceinline__ float pr_max(float v) {
  return fmaxf(v, __shfl_xor(v, 32));
}
__device__ __forceinline__ float pr_add(float v) {
  return v + __shfl_xor(v, 32);
}

__device__ __forceinline__ float fexp2(float x) {
#if __has_builtin(__builtin_amdgcn_exp2f)
  return __builtin_amdgcn_exp2f(x);
#else
  return exp2f(x);
#endif
}

__device__ __forceinline__ f32x4 mfma16(short8 a, short8 b, f32x4 c) {
  return __builtin_amdgcn_mfma_f32_16x16x32_bf16(a, b, c, 0, 0, 0);
}
__device__ __forceinline__ f32x16 mfma32(short8 a, short8 b, f32x16 c) {
  return __builtin_amdgcn_mfma_f32_32x32x16_bf16(a, b, c, 0, 0, 0);
}

// pack 8 f32 P-values into one PV B-frag (k-slice), R3-proven mapping:
//   lower lane: {own w0, own w1, partner w0, partner w1}
//   upper lane: {partner w2, partner w3, own w2, own w3}
__device__ __forceinline__ short8 pack_frag(u32 w0, u32 w1, u32 w2, u32 w3, bool hi) {
  u32 x0 = (u32)__shfl_xor((int)w0, 32), x1 = (u32)__shfl_xor((int)w1, 32);
  u32 x2 = (u32)__shfl_xor((int)w2, 32), x3 = (u32)__shfl_xor((int)w3, 32);
  u32x4 f = { hi ? x2 : w0, hi ? x3 : w1, hi ? w2 : x0, hi ? w3 : x1 };
  return __builtin_bit_cast(short8, f);
}

// ---------------- conversion / transpose kernels ----------------

__global__ void k_conv_x(const float* __restrict__ x, u16* __restrict__ xb, int n) {
  int i = blockIdx.x * 256 + threadIdx.x;
  if (i < n) xb[i] = f2bf(x[i]);
}

__global__ __launch_bounds__(256) void k_transpose_w(const float* __restrict__ w,
                                                     u16* __restrict__ wt,
                                                     int rows, int cols) {
  __shared__ float tile[32][33];
  int tx = threadIdx.x & 31, ty = threadIdx.x >> 5;
  int kb = blockIdx.x * 32;
  int nb = blockIdx.y * 32;
#pragma unroll
  for (int j = 0; j < 4; j++)
    tile[ty + 8 * j][tx] = w[(size_t)(kb + ty + 8 * j) * cols + nb + tx];
  __syncthreads();
#pragma unroll
  for (int j = 0; j < 4; j++)
    wt[(size_t)(nb + ty + 8 * j) * rows + kb + tx] = f2bf(tile[tx][ty + 8 * j]);
}

// ---------------- QKV GEMM + bias + RoPE epilogue ----------------
__global__ __launch_bounds__(256) void k_qkv(const u16* __restrict__ A,
                                             const u16* __restrict__ Bt,
                                             const float* __restrict__ bias,
                                             u16* __restrict__ Qb,
                                             u16* __restrict__ Kb,
                                             u16* __restrict__ Vt) {
  __shared__ u16 As[128][40];
  __shared__ u16 Bs[128][40];
  int t = threadIdx.x;
  int w = t >> 6, lane = t & 63, g = lane >> 4, c = lane & 15;
  int wr = w >> 1, wc = w & 1;
  int bm = blockIdx.x * 128, bn = blockIdx.y * 128;

  f32x4 acc[4][4];
#pragma unroll
  for (int m = 0; m < 4; m++)
#pragma unroll
    for (int n = 0; n < 4; n++) acc[m][n] = (f32x4){0.f, 0.f, 0.f, 0.f};

  int srow = t >> 1, sseg = (t & 1) * 16;
  for (int bk = 0; bk < EMB; bk += 32) {
    const u16* ga = A  + (size_t)(bm + srow) * EMB + bk + sseg;
    const u16* gb = Bt + (size_t)(bn + srow) * EMB + bk + sseg;
    short8 a0 = *(const short8*)ga, a1 = *(const short8*)(ga + 8);
    short8 b0 = *(const short8*)gb, b1 = *(const short8*)(gb + 8);
    __syncthreads();
    *(short8*)&As[srow][sseg] = a0; *(short8*)&As[srow][sseg + 8] = a1;
    *(short8*)&Bs[srow][sseg] = b0; *(short8*)&Bs[srow][sseg + 8] = b1;
    __syncthreads();
    short8 af[4], bf[4];
#pragma unroll
    for (int m = 0; m < 4; m++) af[m] = *(const short8*)&As[wr * 64 + m * 16 + c][g * 8];
#pragma unroll
    for (int n = 0; n < 4; n++) bf[n] = *(const short8*)&Bs[wc * 64 + n * 16 + c][g * 8];
#pragma unroll
    for (int m = 0; m < 4; m++)
#pragma unroll
      for (int n = 0; n < 4; n++) acc[m][n] = mfma16(af[m], bf[n], acc[m][n]);
  }

  int colbase = bn + wc * 64;
  int sec = colbase / EMB;               // 0=Q 1=K 2=V
  int hh  = (colbase % EMB) / DH;
  float qs = (sec == 0) ? QSCALE : 1.0f;
  float invf[2];
#pragma unroll
  for (int n = 0; n < 2; n++) {
    int d1 = n * 16 + c;
    invf[n] = exp2f(-(float)d1 * (13.287712379549449f / 32.0f));
  }
#pragma unroll
  for (int m = 0; m < 4; m++) {
    int rowb = bm + wr * 64 + m * 16 + 4 * g;
#pragma unroll
    for (int e = 0; e < 4; e++) {
      int srw = rowb + e;
      float v[4];
#pragma unroll
      for (int n = 0; n < 4; n++) v[n] = acc[m][n][e] + bias[colbase + n * 16 + c];
      if (sec == 2) {
#pragma unroll
        for (int n = 0; n < 4; n++)
          Vt[(size_t)(hh * DH + n * 16 + c) * S_LEN + srw] = f2bf(v[n]);
      } else {
        u16* dst = (sec == 0) ? Qb : Kb;
        size_t base = ((size_t)hh * S_LEN + srw) * DH;
#pragma unroll
        for (int n = 0; n < 2; n++) {
          int d1 = n * 16 + c;
          float ang = (float)srw * invf[n];
          float sn, cs;
          sincosf(ang, &sn, &cs);
          float o1 = (v[n] * cs - v[n + 2] * sn) * qs;
          float o2 = (v[n + 2] * cs + v[n] * sn) * qs;
          dst[base + d1]      = f2bf(o1);
          dst[base + d1 + 32] = f2bf(o2);
        }
      }
    }
  }
}

// ---------------- flash attention ----------------
// Swapped-operand, LDS-free tiles; 4-wave KV split per 32-row Q block.
// Pair-tile main loop (KVBLK=64): batched K loads, one max-reduce/rescale
// check per 64 scores, V loads issued before softmax.

template<bool MASKED>
__device__ __forceinline__ void attn_tile(int kv0, int qi, int half,
    const u16* __restrict__ Kh, const u16* __restrict__ Vh,
    short8 qf0, short8 qf1, short8 qf2, short8 qf3,
    f32x16& acc0, f32x16& acc1, float& m, float& l) {
  const u16* kp = Kh + (size_t)(kv0 + qi) * DH + half * 8;
  short8 k0 = *(const short8*)(kp);
  short8 k1 = *(const short8*)(kp + 16);
  short8 k2 = *(const short8*)(kp + 32);
  short8 k3 = *(const short8*)(kp + 48);
  __builtin_amdgcn_s_setprio(1);
  f32x16 sc = {0,0,0,0,0,0,0,0,0,0,0,0,0,0,0,0};
  sc = mfma32(k0, qf0, sc);
  sc = mfma32(k1, qf1, sc);
  sc = mfma32(k2, qf2, sc);
  sc = mfma32(k3, qf3, sc);
  __builtin_amdgcn_s_setprio(0);
  const u16* vp = Vh + (size_t)qi * S_LEN + kv0 + half * 8;
  short8 v00 = *(const short8*)(vp);
  short8 v01 = *(const short8*)(vp + 16);
  short8 v10 = *(const short8*)(vp + (size_t)32 * S_LEN);
  short8 v11 = *(const short8*)(vp + (size_t)32 * S_LEN + 16);
  if (MASKED) {
#pragma unroll
    for (int i = 0; i < 16; i++) {
      int kl = (i & 3) + 8 * (i >> 2) + 4 * half;
      if (kl > qi) sc[i] = -1e30f;
    }
  }
  float t0 = fmaxf(fmaxf(sc[0], sc[1]), fmaxf(sc[2], sc[3]));
  float t1 = fmaxf(fmaxf(sc[4], sc[5]), fmaxf(sc[6], sc[7]));
  float t2 = fmaxf(fmaxf(sc[8], sc[9]), fmaxf(sc[10], sc[11]));
  float t3 = fmaxf(fmaxf(sc[12], sc[13]), fmaxf(sc[14], sc[15]));
  float rmax = pr_max(fmaxf(fmaxf(t0, t1), fmaxf(t2, t3)));
  if (__any(rmax > m + 8.0f)) {
    float mn = fmaxf(m, rmax);
    float f = fexp2(m - mn);
    m = mn; l *= f;
#pragma unroll
    for (int i = 0; i < 16; i++) { acc0[i] *= f; acc1[i] *= f; }
  }
  f32x16 p;
#pragma unroll
  for (int i = 0; i < 16; i++) p[i] = fexp2(sc[i] - m);
  l += ((p[0] + p[1]) + (p[2] + p[3])) + ((p[4] + p[5]) + (p[6] + p[7]))
     + ((p[8] + p[9]) + (p[10] + p[11])) + ((p[12] + p[13]) + (p[14] + p[15]));
  bool hi = (half != 0);
  short8 pa0 = pack_frag(cvtpk(p[0], p[1]),   cvtpk(p[2], p[3]),
                         cvtpk(p[4], p[5]),   cvtpk(p[6], p[7]), hi);
  short8 pa1 = pack_frag(cvtpk(p[8], p[9]),   cvtpk(p[10], p[11]),
                         cvtpk(p[12], p[13]), cvtpk(p[14], p[15]), hi);
  __builtin_amdgcn_s_setprio(1);
  acc0 = mfma32(v00, pa0, acc0);
  acc0 = mfma32(v01, pa1, acc0);
  acc1 = mfma32(v10, pa0, acc1);
  acc1 = mfma32(v11, pa1, acc1);
  __builtin_amdgcn_s_setprio(0);
}

// two unmasked 32-KV tiles per call
__device__ __forceinline__ void attn_tile2(int kv0, int qi, int half,
    const u16* __restrict__ Kh, const u16* __restrict__ Vh,
    short8 qf0, short8 qf1, short8 qf2, short8 qf3,
    f32x16& acc0, f32x16& acc1, float& m, float& l) {
  const u16* kpa = Kh + (size_t)(kv0 + qi) * DH + half * 8;
  const u16* kpb = kpa + (size_t)32 * DH;
  short8 ka0 = *(const short8*)(kpa);
  short8 ka1 = *(const short8*)(kpa + 16);
  short8 ka2 = *(const short8*)(kpa + 32);
  short8 ka3 = *(const short8*)(kpa + 48);
  short8 kb0 = *(const short8*)(kpb);
  short8 kb1 = *(const short8*)(kpb + 16);
  short8 kb2 = *(const short8*)(kpb + 32);
  short8 kb3 = *(const short8*)(kpb + 48);
  __builtin_amdgcn_s_setprio(1);
  f32x16 sa = {0,0,0,0,0,0,0,0,0,0,0,0,0,0,0,0};
  f32x16 sb = {0,0,0,0,0,0,0,0,0,0,0,0,0,0,0,0};
  sa = mfma32(ka0, qf0, sa);
  sb = mfma32(kb0, qf0, sb);
  sa = mfma32(ka1, qf1, sa);
  sb = mfma32(kb1, qf1, sb);
  sa = mfma32(ka2, qf2, sa);
  sb = mfma32(kb2, qf2, sb);
  sa = mfma32(ka3, qf3, sa);
  sb = mfma32(kb3, qf3, sb);
  __builtin_amdgcn_s_setprio(0);
  // issue V loads for both sub-tiles; latency hides under softmax
  const u16* vpa = Vh + (size_t)qi * S_LEN + kv0 + half * 8;
  const u16* vpb = vpa + 32;
  short8 va00 = *(const short8*)(vpa);
  short8 va01 = *(const short8*)(vpa + 16);
  short8 va10 = *(const short8*)(vpa + (size_t)32 * S_LEN);
  short8 va11 = *(const short8*)(vpa + (size_t)32 * S_LEN + 16);
  short8 vb00 = *(const short8*)(vpb);
  short8 vb01 = *(const short8*)(vpb + 16);
  short8 vb10 = *(const short8*)(vpb + (size_t)32 * S_LEN);
  short8 vb11 = *(const short8*)(vpb + (size_t)32 * S_LEN + 16);
  // combined max over both sub-tiles
  float t0 = fmaxf(fmaxf(sa[0], sa[1]), fmaxf(sa[2], sa[3]));
  float t1 = fmaxf(fmaxf(sa[4], sa[5]), fmaxf(sa[6], sa[7]));
  float t2 = fmaxf(fmaxf(sa[8], sa[9]), fmaxf(sa[10], sa[11]));
  float t3 = fmaxf(fmaxf(sa[12], sa[13]), fmaxf(sa[14], sa[15]));
  float u0 = fmaxf(fmaxf(sb[0], sb[1]), fmaxf(sb[2], sb[3]));
  float u1 = fmaxf(fmaxf(sb[4], sb[5]), fmaxf(sb[6], sb[7]));
  float u2 = fmaxf(fmaxf(sb[8], sb[9]), fmaxf(sb[10], sb[11]));
  float u3 = fmaxf(fmaxf(sb[12], sb[13]), fmaxf(sb[14], sb[15]));
  float rmax = pr_max(fmaxf(fmaxf(fmaxf(t0, t1), fmaxf(t2, t3)),
                            fmaxf(fmaxf(u0, u1), fmaxf(u2, u3))));
  if (__any(rmax > m + 8.0f)) {
    float mn = fmaxf(m, rmax);
    float f = fexp2(m - mn);
    m = mn; l *= f;
#pragma unroll
    for (int i = 0; i < 16; i++) { acc0[i] *= f; acc1[i] *= f; }
  }
  f32x16 pa, pb;
#pragma unroll
  for (int i = 0; i < 16; i++) pa[i] = fexp2(sa[i] - m);
#pragma unroll
  for (int i = 0; i < 16; i++) pb[i] = fexp2(sb[i] - m);
  float la = ((pa[0] + pa[1]) + (pa[2] + pa[3])) + ((pa[4] + pa[5]) + (pa[6] + pa[7]))
           + ((pa[8] + pa[9]) + (pa[10] + pa[11])) + ((pa[12] + pa[13]) + (pa[14] + pa[15]));
  float lb = ((pb[0] + pb[1]) + (pb[2] + pb[3])) + ((pb[4] + pb[5]) + (pb[6] + pb[7]))
           + ((pb[8] + pb[9]) + (pb[10] + pb[11])) + ((pb[12] + pb[13]) + (pb[14] + pb[15]));
  l += la + lb;
  bool hi = (half != 0);
  short8 fa0 = pack_frag(cvtpk(pa[0], pa[1]),   cvtpk(pa[2], pa[3]),
                         cvtpk(pa[4], pa[5]),   cvtpk(pa[6], pa[7]), hi);
  short8 fa1 = pack_frag(cvtpk(pa[8], pa[9]),   cvtpk(pa[10], pa[11]),
                         cvtpk(pa[12], pa[13]), cvtpk(pa[14], pa[15]), hi);
  short8 fb0 = pack_frag(cvtpk(pb[0], pb[1]),   cvtpk(pb[2], pb[3]),
                         cvtpk(pb[4], pb[5]),   cvtpk(pb[6], pb[7]), hi);
  short8 fb1 = pack_frag(cvtpk(pb[8], pb[9]),   cvtpk(pb[10], pb[11]),
                         cvtpk(pb[12], pb[13]), cvtpk(pb[14], pb[15]), hi);
  __builtin_amdgcn_s_setprio(1);
  acc0 = mfma32(va00, fa0, acc0);
  acc1 = mfma32(va10, fa0, acc1);
  acc0 = mfma32(va01, fa1, acc0);
  acc1 = mfma32(va11, fa1, acc1);
  acc0 = mfma32(vb00, fb0, acc0);
  acc1 = mfma32(vb10, fb0, acc1);
  acc0 = mfma32(vb01, fb1, acc0);
  acc1 = mfma32(vb11, fb1, acc1);
  __builtin_amdgcn_s_setprio(0);
}

__global__ __launch_bounds__(256, 3) void k_attn(const u16* __restrict__ Q,
                                                 const u16* __restrict__ K,
                                                 const u16* __restrict__ Vt,
                                                 u16* __restrict__ O) {
  __shared__ float Lacc[3][64][33];
  __shared__ float Lml[2][3][32];

  int t = threadIdx.x;
  int w = t >> 6, lane = t & 63;
  int qi = lane & 31, half = lane >> 5;
  int b = blockIdx.x;
  int h = b % NH;
  int qb = 127 - b / NH;              // longest blocks first

  const u16* Qh = Q  + (size_t)h * S_LEN * DH;
  const u16* Kh = K  + (size_t)h * S_LEN * DH;
  const u16* Vh = Vt + (size_t)h * DH * S_LEN;

  const u16* qp = Qh + (size_t)(qb * 32 + qi) * DH + half * 8;
  short8 qf0 = *(const short8*)(qp);
  short8 qf1 = *(const short8*)(qp + 16);
  short8 qf2 = *(const short8*)(qp + 32);
  short8 qf3 = *(const short8*)(qp + 48);

  f32x16 acc0 = {0,0,0,0,0,0,0,0,0,0,0,0,0,0,0,0};
  f32x16 acc1 = {0,0,0,0,0,0,0,0,0,0,0,0,0,0,0,0};
  float m = -1e30f, l = 0.f;

  int nt = qb + 1;                     // total KV tiles (last one masked)
  int ck = (nt + 3) >> 2;              // tiles per wave
  int start = w * ck;
  int end   = min(start + ck, nt);
  int endu  = min(end, nt - 1);        // unmasked range end
  int tt = start;
#pragma unroll 1
  for (; tt + 1 < endu; tt += 2)
    attn_tile2(tt * 32, qi, half, Kh, Vh, qf0, qf1, qf2, qf3, acc0, acc1, m, l);
  for (; tt < endu; tt++)
    attn_tile<false>(tt * 32, qi, half, Kh, Vh, qf0, qf1, qf2, qf3, acc0, acc1, m, l);
  if (start < nt && end == nt)
    attn_tile<true>((nt - 1) * 32, qi, half, Kh, Vh, qf0, qf1, qf2, qf3, acc0, acc1, m, l);

  // cross-wave merge
  float l2 = pr_add(l);
  if (w > 0) {
#pragma unroll
    for (int i = 0; i < 16; i++) {
      Lacc[w - 1][lane][i]      = acc0[i];
      Lacc[w - 1][lane][16 + i] = acc1[i];
    }
    if (half == 0) { Lml[0][w - 1][qi] = m; Lml[1][w - 1][qi] = l2; }
  }
  __syncthreads();
  if (w == 0) {
    float mw[3], lw[3];
    float M = m;
#pragma unroll
    for (int j = 0; j < 3; j++) { mw[j] = Lml[0][j][qi]; lw[j] = Lml[1][j][qi]; M = fmaxf(M, mw[j]); }
    float f0 = fexp2(m - M);
    float ltot = l2 * f0;
#pragma unroll
    for (int i = 0; i < 16; i++) { acc0[i] *= f0; acc1[i] *= f0; }
#pragma unroll
    for (int j = 0; j < 3; j++) {
      float fj = fexp2(mw[j] - M);
      ltot += lw[j] * fj;
#pragma unroll
      for (int i = 0; i < 16; i++) {
        acc0[i] += fj * Lacc[j][lane][i];
        acc1[i] += fj * Lacc[j][lane][16 + i];
      }
    }
    float rl = 1.0f / ltot;
    u16* orow = O + (size_t)(qb * 32 + qi) * EMB + h * DH;
#pragma unroll
    for (int i = 0; i < 16; i += 2) {
      int dl = (i & 3) + 8 * (i >> 2) + 4 * half;
      u32 wa = cvtpk(acc0[i] * rl, acc0[i + 1] * rl);
      u32 wb = cvtpk(acc1[i] * rl, acc1[i + 1] * rl);
      *(u32*)(orow + dl)      = wa;
      *(u32*)(orow + 32 + dl) = wb;
    }
  }
}

// ---------------- output projection ----------------
__global__ __launch_bounds__(256) void k_out(const u16* __restrict__ A,
                                             const u16* __restrict__ Bt,
                                             const float* __restrict__ bias,
                                             float* __restrict__ out) {
  __shared__ u16 As[128][40];
  __shared__ u16 Bs[128][40];
  int t = threadIdx.x;
  int w = t >> 6, lane = t & 63, g = lane >> 4, c = lane & 15;
  int wr = w >> 1, wc = w & 1;
  int bm = blockIdx.x * 128, bn = blockIdx.y * 128;

  f32x4 acc[4][4];
#pragma unroll
  for (int m = 0; m < 4; m++)
#pragma unroll
    for (int n = 0; n < 4; n++) acc[m][n] = (f32x4){0.f, 0.f, 0.f, 0.f};

  int srow = t >> 1, sseg = (t & 1) * 16;
  for (int bk = 0; bk < EMB; bk += 32) {
    const u16* ga = A  + (size_t)(bm + srow) * EMB + bk + sseg;
    const u16* gb = Bt + (size_t)(bn + srow) * EMB + bk + sseg;
    short8 a0 = *(const short8*)ga, a1 = *(const short8*)(ga + 8);
    short8 b0 = *(const short8*)gb, b1 = *(const short8*)(gb + 8);
    __syncthreads();
    *(short8*)&As[srow][sseg] = a0; *(short8*)&As[srow][sseg + 8] = a1;
    *(short8*)&Bs[srow][sseg] = b0; *(short8*)&Bs[srow][sseg + 8] = b1;
    __syncthreads();
    short8 af[4], bf[4];
#pragma unroll
    for (int m = 0; m < 4; m++) af[m] = *(const short8*)&As[wr * 64 + m * 16 + c][g * 8];
#pragma unroll
    for (int n = 0; n < 4; n++) bf[n] = *(const short8*)&Bs[wc * 64 + n * 16 + c][g * 8];
#pragma unroll
    for (int m = 0; m < 4; m++)
#pragma unroll
      for (int n = 0; n < 4; n++) acc[m][n] = mfma16(af[m], bf[n], acc[m][n]);
  }
  int colbase = bn + wc * 64;
#pragma unroll
  for (int m = 0; m < 4; m++) {
    int rowb = bm + wr * 64 + m * 16 + 4 * g;
#pragma unroll
    for (int e = 0; e < 4; e++) {
      int srw = rowb + e;
#pragma unroll
      for (int n = 0; n < 4; n++) {
        int col = colbase + n * 16 + c;
        out[(size_t)srw * EMB + col] = acc[m][n][e] + bias[col];
      }
    }
  }
}

// ---------------- launcher ----------------

extern "C" void kernel_launch(void* const* d_in, const int* in_sizes, int n_in,
                              void* d_out, int out_size, void* d_ws, size_t ws_size,
                              hipStream_t stream) {
  const float* x    = (const float*)d_in[0];
  const float* Wqkv = (const float*)d_in[2];
  const float* bqkv = (const float*)d_in[3];
  const float* Wout = (const float*)d_in[4];
  const float* bout = (const float*)d_in[5];
  float* out = (float*)d_out;

  char* ws = (char*)d_ws;
  u16* xb     = (u16*)(ws);
  u16* wqkvt  = (u16*)(ws + 6291456);
  u16* woutt  = (u16*)(ws + 9830400);
  u16* Qb     = (u16*)(ws + 11010048);
  u16* Kb     = (u16*)(ws + 17301504);
  u16* Vtb    = (u16*)(ws + 23592960);
  u16* Ob     = (u16*)(ws + 29884416);

  k_conv_x<<<(S_LEN * EMB + 255) / 256, 256, 0, stream>>>(x, xb, S_LEN * EMB);
  k_transpose_w<<<dim3(EMB / 32, 3 * EMB / 32), 256, 0, stream>>>(Wqkv, wqkvt, EMB, 3 * EMB);
  k_transpose_w<<<dim3(EMB / 32, EMB / 32), 256, 0, stream>>>(Wout, woutt, EMB, EMB);

  k_qkv<<<dim3(32, 18), 256, 0, stream>>>(xb, wqkvt, bqkv, Qb, Kb, Vtb);
  k_attn<<<NH * 128, 256, 0, stream>>>(Qb, Kb, Vtb, Ob);
  k_out<<<dim3(32, 6), 256, 0, stream>>>(Ob, woutt, bout, out);
}